// Round 7
// baseline (61.252 us; speedup 1.0000x reference)
//
#include <hip/hip_runtime.h>
#include <math.h>

// force = MLP(|dr|) is piecewise-linear in the scalar edge length -> dense
// fp32 table of force(d) on [0, R]; per-edge work = gather + lerp.
//
// Round-7: k3bin (782 blocks, 4 edges/thread) computes msg + counting-sorts
// 1024 edges by dst-range into a 12 KB LDS staging buffer, then writes it
// out with coalesced float4 stores (no scattered global writes, no global
// atomics). k3scat (range r, slice p) consumes runs of blocks b%8==p via an
// LDS run-prefix + per-thread binary search (dense lanes), accumulates in a
// 32 KB LDS tile, plain-stores partial copy p. k4 sums 8 partials - gamma*v.

#define M_TAB 4096
#define EPSF 1e-12f
#define N_OUT 200000
#define RANGE_N 4096
#define RSHIFT 12
#define NBUCK 32
#define P_SL 8
#define NBM 128
#define BCHUNK 1024
#define MAXRUN 136

#define WS_BM_OFF 0
#define WS_TABLE_OFF 1024

// K1: per-block max of ||x_i||^2 -> bm[blockIdx.x].
__global__ __launch_bounds__(256) void k1_maxnorm(const float* __restrict__ x,
                                                  float* __restrict__ bm,
                                                  int n) {
  __shared__ float red[256];
  int tid = threadIdx.x;
  float m = 0.f;
  for (int i = blockIdx.x * blockDim.x + tid; i < n;
       i += gridDim.x * blockDim.x) {
    float2 p = ((const float2*)x)[i];
    m = fmaxf(m, fmaf(p.x, p.x, p.y * p.y));
  }
  red[tid] = m;
  __syncthreads();
  for (int s = 128; s > 0; s >>= 1) {
    if (tid < s) red[tid] = fmaxf(red[tid], red[tid + s]);
    __syncthreads();
  }
  if (tid == 0) bm[blockIdx.x] = red[0];
}

// K2: table[i] = MLP(i * R/(M_TAB-1)) in exact fp32.
__global__ __launch_bounds__(128) void k2_table(
    const float* __restrict__ W0, const float* __restrict__ b0,
    const float* __restrict__ W1, const float* __restrict__ b1,
    const float* __restrict__ W2, const float* __restrict__ b2,
    const float* __restrict__ W3, const float* __restrict__ b3,
    const float* __restrict__ bm, float* __restrict__ table) {
  __shared__ float bufA[128 * 8];
  __shared__ float bufB[128 * 8];
  const int j = threadIdx.x;

  bufA[j] = bm[j];
  __syncthreads();
  for (int st = 64; st > 0; st >>= 1) {
    if (j < st) bufA[j] = fmaxf(bufA[j], bufA[j + st]);
    __syncthreads();
  }
  const float R = fmaxf(2.f * sqrtf(bufA[0]), 1e-20f);
  __syncthreads();

  const float step = R / (float)(M_TAB - 1);
  const int base = blockIdx.x * 8;

  {
    float w = W0[j], b = b0[j];
#pragma unroll
    for (int p = 0; p < 8; ++p)
      bufA[j * 8 + p] = fmaxf(fmaf((float)(base + p) * step, w, b), 0.f);
  }
  __syncthreads();

  float acc[8];
  {
    float b = b1[j];
#pragma unroll
    for (int p = 0; p < 8; ++p) acc[p] = b;
#pragma unroll 8
    for (int k = 0; k < 128; ++k) {
      float w = W1[k * 128 + j];
      float4 h0 = *(const float4*)&bufA[k * 8];
      float4 h1 = *(const float4*)&bufA[k * 8 + 4];
      acc[0] = fmaf(h0.x, w, acc[0]);
      acc[1] = fmaf(h0.y, w, acc[1]);
      acc[2] = fmaf(h0.z, w, acc[2]);
      acc[3] = fmaf(h0.w, w, acc[3]);
      acc[4] = fmaf(h1.x, w, acc[4]);
      acc[5] = fmaf(h1.y, w, acc[5]);
      acc[6] = fmaf(h1.z, w, acc[6]);
      acc[7] = fmaf(h1.w, w, acc[7]);
    }
#pragma unroll
    for (int p = 0; p < 8; ++p) bufB[j * 8 + p] = fmaxf(acc[p], 0.f);
  }
  __syncthreads();

  {
    float b = b2[j];
#pragma unroll
    for (int p = 0; p < 8; ++p) acc[p] = b;
#pragma unroll 8
    for (int k = 0; k < 128; ++k) {
      float w = W2[k * 128 + j];
      float4 h0 = *(const float4*)&bufB[k * 8];
      float4 h1 = *(const float4*)&bufB[k * 8 + 4];
      acc[0] = fmaf(h0.x, w, acc[0]);
      acc[1] = fmaf(h0.y, w, acc[1]);
      acc[2] = fmaf(h0.z, w, acc[2]);
      acc[3] = fmaf(h0.w, w, acc[3]);
      acc[4] = fmaf(h1.x, w, acc[4]);
      acc[5] = fmaf(h1.y, w, acc[5]);
      acc[6] = fmaf(h1.z, w, acc[6]);
      acc[7] = fmaf(h1.w, w, acc[7]);
    }
    float w3 = W3[j];
#pragma unroll
    for (int p = 0; p < 8; ++p) bufA[j * 8 + p] = fmaxf(acc[p], 0.f) * w3;
  }
  __syncthreads();

  for (int s = 64; s > 0; s >>= 1) {
    if (j < s) {
#pragma unroll
      for (int p = 0; p < 8; ++p) bufA[j * 8 + p] += bufA[(j + s) * 8 + p];
    }
    __syncthreads();
  }
  if (j < 8) table[base + j] = bufA[j] + b3[0];
}

__device__ __forceinline__ void edge_msg(const float* __restrict__ x,
                                         const float* __restrict__ table,
                                         float inv_step, int s, int t,
                                         float& vx, float& vy) {
  float2 xs = ((const float2*)x)[s];
  float2 xt = ((const float2*)x)[t];
  float dx = xt.x - xs.x, dy = xt.y - xs.y;
  float d = sqrtf(fmaf(dx, dx, dy * dy));
  float u = fminf(d * inv_step, (float)(M_TAB - 1));
  int i0 = (int)u;
  if (i0 > M_TAB - 2) i0 = M_TAB - 2;
  float frac = u - (float)i0;
  float f0 = table[i0], f1 = table[i0 + 1];
  float f = fmaf(frac, f1 - f0, f0);
  float sc = f / fmaxf(d, EPSF);
  vx = sc * dx;
  vy = sc * dy;
}

// K3bin: block b owns edges [b*1024, b*1024+1024). Compute msg, counting-
// sort by dst-range into LDS stage, coalesced-write to its own bin region.
__global__ __launch_bounds__(256) void k3bin(
    const float* __restrict__ x, const int* __restrict__ src,
    const int* __restrict__ dst, const float* __restrict__ table,
    const float* __restrict__ bm, float* __restrict__ binData,
    int* __restrict__ cntTab, int* __restrict__ offTab, int E) {
  __shared__ float red[NBM];
  __shared__ int cntL[NBUCK];
  __shared__ int offL[NBUCK];
  __shared__ float stage[BCHUNK * 3];  // 12 KB
  const int tid = threadIdx.x;

  if (tid < NBM) red[tid] = bm[tid];
  if (tid < NBUCK) cntL[tid] = 0;
  __syncthreads();
  for (int st = NBM / 2; st > 0; st >>= 1) {
    if (tid < st) red[tid] = fmaxf(red[tid], red[tid + st]);
    __syncthreads();
  }
  const float R = fmaxf(2.f * sqrtf(red[0]), 1e-20f);
  const float inv_step = (float)(M_TAB - 1) / R;

  const int e0 = blockIdx.x * BCHUNK + tid * 4;
  int mdst[4], mrank[4];
  float mvx[4], mvy[4];
  {
    int msrc[4];
    if (e0 + 3 < E) {
      int4 a = *(const int4*)(src + e0);
      int4 c = *(const int4*)(dst + e0);
      msrc[0] = a.x; msrc[1] = a.y; msrc[2] = a.z; msrc[3] = a.w;
      mdst[0] = c.x; mdst[1] = c.y; mdst[2] = c.z; mdst[3] = c.w;
    } else {
#pragma unroll
      for (int i = 0; i < 4; ++i) {
        bool v = (e0 + i < E);
        msrc[i] = v ? src[e0 + i] : 0;
        mdst[i] = v ? dst[e0 + i] : -1;
      }
    }
#pragma unroll
    for (int i = 0; i < 4; ++i) {
      if (mdst[i] >= 0) {
        mrank[i] = atomicAdd(&cntL[mdst[i] >> RSHIFT], 1);
        edge_msg(x, table, inv_step, msrc[i], mdst[i], mvx[i], mvy[i]);
      }
    }
  }
  __syncthreads();
  if (tid == 0) {
    int s = 0;
#pragma unroll
    for (int k = 0; k < NBUCK; ++k) {
      offL[k] = s;
      s += cntL[k];
    }
  }
  __syncthreads();
  if (tid < NBUCK) {
    cntTab[blockIdx.x * NBUCK + tid] = cntL[tid];
    offTab[blockIdx.x * NBUCK + tid] = offL[tid];
  }
  // Scatter into LDS stage (entry = 3 floats: bitcast dloc, vx, vy).
#pragma unroll
  for (int i = 0; i < 4; ++i) {
    if (mdst[i] >= 0) {
      int pos = (offL[mdst[i] >> RSHIFT] + mrank[i]) * 3;
      stage[pos] = __int_as_float(mdst[i] & (RANGE_N - 1));
      stage[pos + 1] = mvx[i];
      stage[pos + 2] = mvy[i];
    }
  }
  __syncthreads();
  // Coalesced write-out of the used prefix.
  const int Ttot = offL[NBUCK - 1] + cntL[NBUCK - 1];
  float* gout = binData + (size_t)blockIdx.x * (BCHUNK * 3);
  if (Ttot == BCHUNK) {
    float4* g4 = (float4*)gout;
    const float4* s4 = (const float4*)stage;
#pragma unroll
    for (int i = 0; i < 3; ++i) g4[tid + i * 256] = s4[tid + i * 256];
  } else {
    for (int i = tid; i < Ttot * 3; i += 256) gout[i] = stage[i];
  }
}

// K3scat: block (r = bid>>3, p = bid&7): consume runs of binning blocks
// b%8==p, bucket r. LDS run-prefix + binary search -> dense lanes.
__global__ __launch_bounds__(512) void k3scat(
    const float* __restrict__ binData, const int* __restrict__ cntTab,
    const int* __restrict__ offTab, float* __restrict__ partial, int NB,
    int n_nodes) {
  __shared__ float acc[RANGE_N * 2];  // 32 KB
  __shared__ int runStart[MAXRUN];
  __shared__ int pref[MAXRUN + 1];
  const int tid = threadIdx.x;
  const int p = blockIdx.x & (P_SL - 1);
  const int r = blockIdx.x >> 3;

  for (int i = tid; i < RANGE_N * 2; i += 512) acc[i] = 0.f;
  const int nrun = (NB - p + P_SL - 1) / P_SL;
  for (int j = tid; j < nrun; j += 512) {
    int b = p + j * P_SL;
    runStart[j] = b * BCHUNK + offTab[b * NBUCK + r];
    pref[j + 1] = cntTab[b * NBUCK + r];  // lengths, prefixed below
  }
  __syncthreads();
  if (tid == 0) {
    pref[0] = 0;
    for (int j = 0; j < nrun; ++j) pref[j + 1] += pref[j];
  }
  __syncthreads();

  const int T = pref[nrun];
  for (int g = tid; g < T; g += 512) {
    // binary search: j with pref[j] <= g < pref[j+1]
    int lo = 0, hi = nrun;
    while (hi - lo > 1) {
      int mid = (lo + hi) >> 1;
      if (pref[mid] <= g) lo = mid; else hi = mid;
    }
    size_t idx = (size_t)(runStart[lo] + (g - pref[lo])) * 3;
    float f0 = binData[idx];
    float vx = binData[idx + 1];
    float vy = binData[idx + 2];
    int dloc = __float_as_int(f0);
    atomicAdd(&acc[dloc * 2], vx);
    atomicAdd(&acc[dloc * 2 + 1], vy);
  }
  __syncthreads();

  const int node0 = r * RANGE_N;
  const int cnt2 = min(RANGE_N, n_nodes - node0);
  float2* po = (float2*)(partial + (size_t)p * N_OUT) + node0;
  const float2* a2 = (const float2*)acc;
  for (int i = tid; i < cnt2; i += 512) po[i] = a2[i];
}

// K3 fallback: direct device-scope atomics (tiny d_ws only).
__global__ __launch_bounds__(256) void k3_direct(
    const float* __restrict__ x, const int* __restrict__ src,
    const int* __restrict__ dst, const float* __restrict__ table,
    const float* __restrict__ bm, float* __restrict__ out, int E) {
  __shared__ float red[NBM];
  int tid = threadIdx.x;
  if (tid < NBM) red[tid] = bm[tid];
  __syncthreads();
  for (int st = NBM / 2; st > 0; st >>= 1) {
    if (tid < st) red[tid] = fmaxf(red[tid], red[tid + st]);
    __syncthreads();
  }
  float R = fmaxf(2.f * sqrtf(red[0]), 1e-20f);
  float inv_step = (float)(M_TAB - 1) / R;
  int e = blockIdx.x * blockDim.x + tid;
  if (e >= E) return;
  int s = src[e], t = dst[e];
  float vx, vy;
  edge_msg(x, table, inv_step, s, t, vx, vy);
  atomicAdd(&out[2 * t + 0], vx);
  atomicAdd(&out[2 * t + 1], vy);
}

// K0 (fallback only): out = -gamma*v.
__global__ __launch_bounds__(256) void k0_init(const float* __restrict__ v,
                                               const float* __restrict__ gamma,
                                               float* __restrict__ out,
                                               int n) {
  int i = blockIdx.x * blockDim.x + threadIdx.x;
  if (i < n) out[i] = -gamma[0] * v[i];
}

// K4: out = -gamma*v + sum_{p<8} partial[p].
__global__ __launch_bounds__(256) void k4_finish(
    const float4* __restrict__ v4, const float* __restrict__ gamma,
    const float4* __restrict__ part4, float4* __restrict__ out4, int n4) {
  int i = blockIdx.x * blockDim.x + threadIdx.x;
  if (i >= n4) return;
  float g = -gamma[0];
  float4 a = v4[i];
  float4 acc = make_float4(g * a.x, g * a.y, g * a.z, g * a.w);
#pragma unroll
  for (int c = 0; c < P_SL; ++c) {
    float4 p = part4[(size_t)c * (N_OUT / 4) + i];
    acc.x += p.x;
    acc.y += p.y;
    acc.z += p.z;
    acc.w += p.w;
  }
  out4[i] = acc;
}

extern "C" void kernel_launch(void* const* d_in, const int* in_sizes, int n_in,
                              void* d_out, int out_size, void* d_ws,
                              size_t ws_size, hipStream_t stream) {
  const float* x = (const float*)d_in[0];
  const float* v = (const float*)d_in[1];
  const int* src = (const int*)d_in[2];
  const int* dst = (const int*)d_in[3];
  const float* gamma = (const float*)d_in[4];
  const float* W0 = (const float*)d_in[5];
  const float* b0 = (const float*)d_in[6];
  const float* W1 = (const float*)d_in[7];
  const float* b1 = (const float*)d_in[8];
  const float* W2 = (const float*)d_in[9];
  const float* b2 = (const float*)d_in[10];
  const float* W3 = (const float*)d_in[11];
  const float* b3 = (const float*)d_in[12];
  float* out = (float*)d_out;
  float* bm = (float*)((char*)d_ws + WS_BM_OFF);
  float* table = (float*)((char*)d_ws + WS_TABLE_OFF);

  int n_out = out_size;           // 200000
  int n_nodes = in_sizes[0] / 2;  // 100000
  int E = in_sizes[2];            // 800000

  const int NB = (E + BCHUNK - 1) / BCHUNK;
  size_t sz_tab = ((size_t)NB * NBUCK * 4 + 255) & ~(size_t)255;
  size_t off_cnt = 65536;
  size_t off_off = off_cnt + sz_tab;
  size_t off_part = off_off + sz_tab;
  size_t off_bin = off_part + (size_t)P_SL * N_OUT * 4;
  size_t need = off_bin + (size_t)NB * BCHUNK * 12;

  int NR = (n_nodes + RANGE_N - 1) / RANGE_N;
  bool fast = (ws_size >= need) && (n_out == N_OUT) && (NR <= NBUCK) &&
              (n_nodes <= N_OUT / 2) && (NB <= P_SL * MAXRUN);

  hipLaunchKernelGGL(k1_maxnorm, dim3(NBM), dim3(256), 0, stream, x, bm,
                     n_nodes);
  hipLaunchKernelGGL(k2_table, dim3(M_TAB / 8), dim3(128), 0, stream, W0, b0,
                     W1, b1, W2, b2, W3, b3, bm, table);
  if (fast) {
    int* cntTab = (int*)((char*)d_ws + off_cnt);
    int* offTab = (int*)((char*)d_ws + off_off);
    float* partial = (float*)((char*)d_ws + off_part);
    float* binData = (float*)((char*)d_ws + off_bin);
    hipLaunchKernelGGL(k3bin, dim3(NB), dim3(256), 0, stream, x, src, dst,
                       table, bm, binData, cntTab, offTab, E);
    hipLaunchKernelGGL(k3scat, dim3(NR * P_SL), dim3(512), 0, stream, binData,
                       cntTab, offTab, partial, NB, n_nodes);
    hipLaunchKernelGGL(k4_finish, dim3((N_OUT / 4 + 255) / 256), dim3(256), 0,
                       stream, (const float4*)v, gamma, (const float4*)partial,
                       (float4*)out, N_OUT / 4);
  } else {
    hipLaunchKernelGGL(k0_init, dim3((n_out + 255) / 256), dim3(256), 0,
                       stream, v, gamma, out, n_out);
    hipLaunchKernelGGL(k3_direct, dim3((E + 255) / 256), dim3(256), 0, stream,
                       x, src, dst, table, bm, out, E);
  }
}

// Round 8
// 52.039 us; speedup vs baseline: 1.1770x; 1.1770x over previous
//
#include <hip/hip_runtime.h>
#include <math.h>

// force = MLP(|dr|) is piecewise-linear in the scalar edge length -> dense
// fp32 table of force(d), parameterized by u = d/(1+d) in [0,1) so the grid
// is DATA-INDEPENDENT (no max-reduction kernel needed).
//
// Round-8: 3 kernels / 2 boundaries (was 5/4):
//  k3bin  - bins all edges by dst-range (counting sort into per-block
//           regions, entry = {dloc,dx,dy,u} float4, no global atomics);
//           blocks < 512 ALSO build the 4096-entry table (table work
//           overlaps bin memory latency across blocks).
//  k3scat - block (range r, slice p): dense consume of its runs via LDS
//           run-prefix + binary search; table lerp; 16KB LDS accumulate;
//           plain-store partial copy p.
//  k4     - out = -gamma*v + sum of 8 partials.

#define M_TAB 4096
#define INV_MTAB (1.0f / 4096.0f)
#define EPSF 1e-12f
#define N_OUT 200000
#define RANGE_N 2048
#define RSHIFT 11
#define NBUCK 64
#define P_SL 8
#define BCHUNK 1024
#define MAXRUN 112

#define WS_TABLE_OFF 0

// Shared table builder: 8 grid points per block, thread j (<128) = neuron j.
// Caller guarantees all threads of the block enter (barriers are uniform).
__device__ __forceinline__ void build_table_block(
    int base, int tid, const float* __restrict__ W0,
    const float* __restrict__ b0, const float* __restrict__ W1,
    const float* __restrict__ b1, const float* __restrict__ W2,
    const float* __restrict__ b2, const float* __restrict__ W3,
    const float* __restrict__ b3, float* __restrict__ table, float* bufA,
    float* bufB) {
  const int j = tid;
  if (j < 128) {
    float w = W0[j], b = b0[j];
#pragma unroll
    for (int p = 0; p < 8; ++p) {
      float u = (float)(base + p) * INV_MTAB;
      float dd = u / (1.f - u);
      bufA[j * 8 + p] = fmaxf(fmaf(dd, w, b), 0.f);
    }
  }
  __syncthreads();
  float acc[8];
  if (j < 128) {
    float b = b1[j];
#pragma unroll
    for (int p = 0; p < 8; ++p) acc[p] = b;
#pragma unroll 8
    for (int k = 0; k < 128; ++k) {
      float w = W1[k * 128 + j];
      float4 h0 = *(const float4*)&bufA[k * 8];
      float4 h1 = *(const float4*)&bufA[k * 8 + 4];
      acc[0] = fmaf(h0.x, w, acc[0]);
      acc[1] = fmaf(h0.y, w, acc[1]);
      acc[2] = fmaf(h0.z, w, acc[2]);
      acc[3] = fmaf(h0.w, w, acc[3]);
      acc[4] = fmaf(h1.x, w, acc[4]);
      acc[5] = fmaf(h1.y, w, acc[5]);
      acc[6] = fmaf(h1.z, w, acc[6]);
      acc[7] = fmaf(h1.w, w, acc[7]);
    }
  }
  __syncthreads();
  if (j < 128) {
#pragma unroll
    for (int p = 0; p < 8; ++p) bufB[j * 8 + p] = fmaxf(acc[p], 0.f);
  }
  __syncthreads();
  if (j < 128) {
    float b = b2[j];
#pragma unroll
    for (int p = 0; p < 8; ++p) acc[p] = b;
#pragma unroll 8
    for (int k = 0; k < 128; ++k) {
      float w = W2[k * 128 + j];
      float4 h0 = *(const float4*)&bufB[k * 8];
      float4 h1 = *(const float4*)&bufB[k * 8 + 4];
      acc[0] = fmaf(h0.x, w, acc[0]);
      acc[1] = fmaf(h0.y, w, acc[1]);
      acc[2] = fmaf(h0.z, w, acc[2]);
      acc[3] = fmaf(h0.w, w, acc[3]);
      acc[4] = fmaf(h1.x, w, acc[4]);
      acc[5] = fmaf(h1.y, w, acc[5]);
      acc[6] = fmaf(h1.z, w, acc[6]);
      acc[7] = fmaf(h1.w, w, acc[7]);
    }
    float w3 = W3[j];
#pragma unroll
    for (int p = 0; p < 8; ++p) bufA[j * 8 + p] = fmaxf(acc[p], 0.f) * w3;
  }
  __syncthreads();
  for (int s = 64; s > 0; s >>= 1) {
    if (j < s) {
#pragma unroll
      for (int p = 0; p < 8; ++p) bufA[j * 8 + p] += bufA[(j + s) * 8 + p];
    }
    __syncthreads();
  }
  if (j < 8) table[base + j] = bufA[j] + b3[0];
}

// K3bin: block b bins edges [b*1024, b*1024+1024) by dst-range into its own
// binData region (counting sort, entry = float4{dloc,dx,dy,u}); writes
// cnt/off tables. Blocks < M_TAB/8 also build table chunk [b*8, b*8+8).
__global__ __launch_bounds__(256) void k3bin(
    const float* __restrict__ x, const int* __restrict__ src,
    const int* __restrict__ dst, const float* __restrict__ W0,
    const float* __restrict__ b0, const float* __restrict__ W1,
    const float* __restrict__ b1, const float* __restrict__ W2,
    const float* __restrict__ b2, const float* __restrict__ W3,
    const float* __restrict__ b3, float4* __restrict__ binData,
    int* __restrict__ cntTab, int* __restrict__ offTab,
    float* __restrict__ table, int E) {
  __shared__ int cntL[NBUCK];
  __shared__ int offL[NBUCK];
  __shared__ float bufA[1024];
  __shared__ float bufB[1024];
  const int tid = threadIdx.x;
  if (tid < NBUCK) cntL[tid] = 0;
  __syncthreads();

  const int e0 = blockIdx.x * BCHUNK + tid * 4;
  int msrc[4], mdst[4], mrank[4];
  float mdx[4], mdy[4], mu[4];
  if (e0 + 3 < E) {
    int4 a = *(const int4*)(src + e0);
    int4 c = *(const int4*)(dst + e0);
    msrc[0] = a.x; msrc[1] = a.y; msrc[2] = a.z; msrc[3] = a.w;
    mdst[0] = c.x; mdst[1] = c.y; mdst[2] = c.z; mdst[3] = c.w;
  } else {
#pragma unroll
    for (int i = 0; i < 4; ++i) {
      bool v = (e0 + i < E);
      msrc[i] = v ? src[e0 + i] : 0;
      mdst[i] = v ? dst[e0 + i] : -1;
    }
  }
#pragma unroll
  for (int i = 0; i < 4; ++i) {
    if (mdst[i] >= 0) {
      float2 xs = ((const float2*)x)[msrc[i]];
      float2 xt = ((const float2*)x)[mdst[i]];
      mdx[i] = xt.x - xs.x;
      mdy[i] = xt.y - xs.y;
      float d = sqrtf(fmaf(mdx[i], mdx[i], mdy[i] * mdy[i]));
      mu[i] = d / (1.f + d);
      mrank[i] = atomicAdd(&cntL[mdst[i] >> RSHIFT], 1);
    }
  }
  __syncthreads();
  if (tid == 0) {
    int s = 0;
#pragma unroll
    for (int k = 0; k < NBUCK; ++k) {
      offL[k] = s;
      s += cntL[k];
    }
  }
  __syncthreads();
  if (tid < NBUCK) {
    cntTab[blockIdx.x * NBUCK + tid] = cntL[tid];
    offTab[blockIdx.x * NBUCK + tid] = offL[tid];
  }
  float4* gout = binData + (size_t)blockIdx.x * BCHUNK;
#pragma unroll
  for (int i = 0; i < 4; ++i) {
    if (mdst[i] >= 0) {
      gout[offL[mdst[i] >> RSHIFT] + mrank[i]] =
          make_float4(__int_as_float(mdst[i] & (RANGE_N - 1)), mdx[i], mdy[i],
                      mu[i]);
    }
  }

  if (blockIdx.x < M_TAB / 8)
    build_table_block(blockIdx.x * 8, tid, W0, b0, W1, b1, W2, b2, W3, b3,
                      table, bufA, bufB);
}

// K3scat: block (r = bid>>3, p = bid&7): consume runs of bin-blocks b%8==p
// for bucket r via LDS run-prefix + binary search; table lerp; 16KB LDS
// accumulate; plain-store partial copy p.
__global__ __launch_bounds__(512) void k3scat(
    const float4* __restrict__ binData, const int* __restrict__ cntTab,
    const int* __restrict__ offTab, const float* __restrict__ table,
    float* __restrict__ partial, int NB, int n_nodes) {
  __shared__ float acc[RANGE_N * 2];  // 16 KB
  __shared__ int runStart[MAXRUN];
  __shared__ int pref[MAXRUN + 1];
  const int tid = threadIdx.x;
  const int p = blockIdx.x & (P_SL - 1);
  const int r = blockIdx.x >> 3;

  for (int i = tid; i < RANGE_N * 2; i += 512) acc[i] = 0.f;
  const int nrun = (NB - p + P_SL - 1) / P_SL;
  for (int j = tid; j < nrun; j += 512) {
    int b = p + j * P_SL;
    runStart[j] = b * BCHUNK + offTab[b * NBUCK + r];
    pref[j + 1] = cntTab[b * NBUCK + r];
  }
  __syncthreads();
  if (tid == 0) {
    pref[0] = 0;
    for (int j = 0; j < nrun; ++j) pref[j + 1] += pref[j];
  }
  __syncthreads();

  const int T = pref[nrun];
  for (int g = tid; g < T; g += 512) {
    int lo = 0, hi = nrun;
    while (hi - lo > 1) {
      int mid = (lo + hi) >> 1;
      if (pref[mid] <= g) lo = mid; else hi = mid;
    }
    float4 ent = binData[(size_t)runStart[lo] + (g - pref[lo])];
    int dloc = __float_as_int(ent.x);
    float u = ent.w;
    float idxf = u * (float)M_TAB;
    int i0 = (int)idxf;
    if (i0 > M_TAB - 2) i0 = M_TAB - 2;
    float frac = idxf - (float)i0;
    float f0 = table[i0], f1 = table[i0 + 1];
    float f = fmaf(frac, f1 - f0, f0);
    float d = u / (1.f - u);
    float sc = f / fmaxf(d, EPSF);
    atomicAdd(&acc[dloc * 2], sc * ent.y);
    atomicAdd(&acc[dloc * 2 + 1], sc * ent.z);
  }
  __syncthreads();

  const int node0 = r * RANGE_N;
  const int cnt2 = min(RANGE_N, n_nodes - node0);
  float2* po = (float2*)(partial + (size_t)p * N_OUT) + node0;
  const float2* a2 = (const float2*)acc;
  for (int i = tid; i < cnt2; i += 512) po[i] = a2[i];
}

// K4: out = -gamma*v + sum_{p<8} partial[p].
__global__ __launch_bounds__(256) void k4_finish(
    const float4* __restrict__ v4, const float* __restrict__ gamma,
    const float4* __restrict__ part4, float4* __restrict__ out4, int n4) {
  int i = blockIdx.x * blockDim.x + threadIdx.x;
  if (i >= n4) return;
  float g = -gamma[0];
  float4 a = v4[i];
  float4 acc = make_float4(g * a.x, g * a.y, g * a.z, g * a.w);
#pragma unroll
  for (int c = 0; c < P_SL; ++c) {
    float4 p = part4[(size_t)c * (N_OUT / 4) + i];
    acc.x += p.x;
    acc.y += p.y;
    acc.z += p.z;
    acc.w += p.w;
  }
  out4[i] = acc;
}

// ---- Fallback path (tiny d_ws only) ----
__global__ __launch_bounds__(128) void k2_table(
    const float* __restrict__ W0, const float* __restrict__ b0,
    const float* __restrict__ W1, const float* __restrict__ b1,
    const float* __restrict__ W2, const float* __restrict__ b2,
    const float* __restrict__ W3, const float* __restrict__ b3,
    float* __restrict__ table) {
  __shared__ float bufA[1024];
  __shared__ float bufB[1024];
  build_table_block(blockIdx.x * 8, threadIdx.x, W0, b0, W1, b1, W2, b2, W3,
                    b3, table, bufA, bufB);
}

__global__ __launch_bounds__(256) void k0_init(const float* __restrict__ v,
                                               const float* __restrict__ gamma,
                                               float* __restrict__ out,
                                               int n) {
  int i = blockIdx.x * blockDim.x + threadIdx.x;
  if (i < n) out[i] = -gamma[0] * v[i];
}

__global__ __launch_bounds__(256) void k3_direct(
    const float* __restrict__ x, const int* __restrict__ src,
    const int* __restrict__ dst, const float* __restrict__ table,
    float* __restrict__ out, int E) {
  int e = blockIdx.x * blockDim.x + threadIdx.x;
  if (e >= E) return;
  int s = src[e], t = dst[e];
  float2 xs = ((const float2*)x)[s];
  float2 xt = ((const float2*)x)[t];
  float dx = xt.x - xs.x, dy = xt.y - xs.y;
  float d = sqrtf(fmaf(dx, dx, dy * dy));
  float u = d / (1.f + d);
  float idxf = u * (float)M_TAB;
  int i0 = (int)idxf;
  if (i0 > M_TAB - 2) i0 = M_TAB - 2;
  float frac = idxf - (float)i0;
  float f = fmaf(frac, table[i0 + 1] - table[i0], table[i0]);
  float sc = f / fmaxf(d, EPSF);
  atomicAdd(&out[2 * t + 0], sc * dx);
  atomicAdd(&out[2 * t + 1], sc * dy);
}

extern "C" void kernel_launch(void* const* d_in, const int* in_sizes, int n_in,
                              void* d_out, int out_size, void* d_ws,
                              size_t ws_size, hipStream_t stream) {
  const float* x = (const float*)d_in[0];
  const float* v = (const float*)d_in[1];
  const int* src = (const int*)d_in[2];
  const int* dst = (const int*)d_in[3];
  const float* gamma = (const float*)d_in[4];
  const float* W0 = (const float*)d_in[5];
  const float* b0 = (const float*)d_in[6];
  const float* W1 = (const float*)d_in[7];
  const float* b1 = (const float*)d_in[8];
  const float* W2 = (const float*)d_in[9];
  const float* b2 = (const float*)d_in[10];
  const float* W3 = (const float*)d_in[11];
  const float* b3 = (const float*)d_in[12];
  float* out = (float*)d_out;
  float* table = (float*)((char*)d_ws + WS_TABLE_OFF);

  int n_out = out_size;           // 200000
  int n_nodes = in_sizes[0] / 2;  // 100000
  int E = in_sizes[2];            // 800000

  const int NB = (E + BCHUNK - 1) / BCHUNK;  // 782
  size_t sz_tab = ((size_t)NB * NBUCK * 4 + 255) & ~(size_t)255;
  size_t off_cnt = 65536;
  size_t off_off = off_cnt + sz_tab;
  size_t off_part = off_off + sz_tab;
  size_t off_bin = off_part + (size_t)P_SL * N_OUT * 4;
  size_t need = off_bin + (size_t)NB * BCHUNK * 16;

  const int NR = (n_nodes + RANGE_N - 1) / RANGE_N;  // 49
  bool fast = (ws_size >= need) && (n_out == N_OUT) && (NR <= NBUCK) &&
              (n_nodes <= N_OUT / 2) && (NB <= P_SL * MAXRUN) &&
              (NB >= M_TAB / 8);

  if (fast) {
    int* cntTab = (int*)((char*)d_ws + off_cnt);
    int* offTab = (int*)((char*)d_ws + off_off);
    float* partial = (float*)((char*)d_ws + off_part);
    float4* binData = (float4*)((char*)d_ws + off_bin);
    hipLaunchKernelGGL(k3bin, dim3(NB), dim3(256), 0, stream, x, src, dst, W0,
                       b0, W1, b1, W2, b2, W3, b3, binData, cntTab, offTab,
                       table, E);
    hipLaunchKernelGGL(k3scat, dim3(NR * P_SL), dim3(512), 0, stream, binData,
                       cntTab, offTab, table, partial, NB, n_nodes);
    hipLaunchKernelGGL(k4_finish, dim3((N_OUT / 4 + 255) / 256), dim3(256), 0,
                       stream, (const float4*)v, gamma, (const float4*)partial,
                       (float4*)out, N_OUT / 4);
  } else {
    hipLaunchKernelGGL(k2_table, dim3(M_TAB / 8), dim3(128), 0, stream, W0, b0,
                       W1, b1, W2, b2, W3, b3, table);
    hipLaunchKernelGGL(k0_init, dim3((n_out + 255) / 256), dim3(256), 0,
                       stream, v, gamma, out, n_out);
    hipLaunchKernelGGL(k3_direct, dim3((E + 255) / 256), dim3(256), 0, stream,
                       x, src, dst, table, out, E);
  }
}